// Round 6
// baseline (1139.654 us; speedup 1.0000x reference)
//
#include <hip/hip_runtime.h>

#define DT 0.1f

typedef float v2f __attribute__((ext_vector_type(2)));

// Pack per-hidden-unit weights into one float4: (W1[0][j], W1[1][j], b1[j], W2[j])
__global__ void pack_weights(const float* __restrict__ W1, const float* __restrict__ b1,
                             const float* __restrict__ W2, float4* __restrict__ ws, int hidden) {
    int j = blockIdx.x * blockDim.x + threadIdx.x;
    if (j < hidden) {
        ws[j] = make_float4(W1[j], W1[hidden + j], b1[j], W2[j]);
    }
}

// Guaranteed packed fp32 FMA (v_pk_fma_f32: all operands are 64-bit VGPR pairs).
__device__ __forceinline__ v2f pk_fma(v2f a, v2f b, v2f c) {
    v2f d;
    asm("v_pk_fma_f32 %0, %1, %2, %3" : "=v"(d) : "v"(a), "v"(b), "v"(c));
    return d;
}

// DPP-based add-reduce (VALU pipe). 0xB1=xor1, 0x4E=xor2, 0x141=half-mirror.
template <int CTRL>
__device__ __forceinline__ float dpp_add(float x) {
    int v = __builtin_amdgcn_mov_dpp(__float_as_int(x), CTRL, 0xf, 0xf, true);
    return x + __int_as_float(v);
}

// 8 lanes per element: p = lane & 7 owns hidden units [p*32, (p+1)*32).
// Weights = 64 v2f = 128 regs. Rounds 3/5 showed the allocator homes these in
// AGPRs and v_accvgpr_read's them at every use (VGPR_Count=108, occupancy=2
// waves/SIMD => ~236 total regs, issue ~576cy/wave-step vs ~200cy of work).
// Fix: re-pin them to architectural VGPRs with an empty "+v" asm INSIDE each
// step, making AGPR homes strictly unprofitable.
__global__ __launch_bounds__(256, 2) void waterbalance(
    const float* __restrict__ inflows, const float* __restrict__ storage0,
    const float4* __restrict__ ws, const float* __restrict__ b2,
    float* __restrict__ out_storages, float* __restrict__ out_outflows,
    int iters, int batch)
{
    const int tid = blockIdx.x * blockDim.x + threadIdx.x;
    const int e = tid >> 3;      // element index
    const int p = tid & 7;       // unit-group within element
    if (e >= batch) return;

    v2f wx[16], wy[16], wb[16], w2[16];
    #pragma unroll
    for (int r = 0; r < 16; ++r) {
        float4 a = ws[p * 32 + 2 * r];
        float4 b = ws[p * 32 + 2 * r + 1];
        wx[r] = (v2f){a.x, b.x};
        wy[r] = (v2f){a.y, b.y};
        wb[r] = (v2f){a.z, b.z};
        w2[r] = (v2f){a.w, b.w};
    }

    const float b2v = b2[0];

    float s = storage0[e];
    if (p == 0) out_storages[e] = s;     // storages[0] = storage0

    const float* __restrict__ inp = inflows + e;
    float* __restrict__ po = out_outflows + e;                    // row t
    float* __restrict__ ps = out_storages + (size_t)batch + e;    // row t+1

    const int nchunk = iters >> 2;
    const int tail_start = nchunk << 2;

    // Prefetch chunk 0 (4 steps of inflow in flight).
    float buf[4];
    #pragma unroll
    for (int r = 0; r < 4; ++r) buf[r] = inp[(size_t)r * batch];

    for (int c = 0; c < nchunk; ++c) {
        float nb[4];
        if (c + 1 < nchunk) {
            const float* q = inp + (size_t)(c + 1) * 4 * batch;
            #pragma unroll
            for (int r = 0; r < 4; ++r) nb[r] = q[(size_t)r * batch];
        } else {
            #pragma unroll
            for (int r = 0; r < 4; ++r) nb[r] = 0.0f;
        }

        #pragma unroll
        for (int r = 0; r < 4; ++r) {
            // Pin weights to architectural VGPRs for this iteration (empty asm,
            // zero instructions; defeats AGPR parking + per-use accvgpr_read).
            asm("" : "+v"(wx[0]), "+v"(wx[1]), "+v"(wx[2]), "+v"(wx[3]),
                     "+v"(wx[4]), "+v"(wx[5]), "+v"(wx[6]), "+v"(wx[7]),
                     "+v"(wx[8]), "+v"(wx[9]), "+v"(wx[10]), "+v"(wx[11]),
                     "+v"(wx[12]), "+v"(wx[13]), "+v"(wx[14]), "+v"(wx[15]));
            asm("" : "+v"(wy[0]), "+v"(wy[1]), "+v"(wy[2]), "+v"(wy[3]),
                     "+v"(wy[4]), "+v"(wy[5]), "+v"(wy[6]), "+v"(wy[7]),
                     "+v"(wy[8]), "+v"(wy[9]), "+v"(wy[10]), "+v"(wy[11]),
                     "+v"(wy[12]), "+v"(wy[13]), "+v"(wy[14]), "+v"(wy[15]));
            asm("" : "+v"(wb[0]), "+v"(wb[1]), "+v"(wb[2]), "+v"(wb[3]),
                     "+v"(wb[4]), "+v"(wb[5]), "+v"(wb[6]), "+v"(wb[7]),
                     "+v"(wb[8]), "+v"(wb[9]), "+v"(wb[10]), "+v"(wb[11]),
                     "+v"(wb[12]), "+v"(wb[13]), "+v"(wb[14]), "+v"(wb[15]));
            asm("" : "+v"(w2[0]), "+v"(w2[1]), "+v"(w2[2]), "+v"(w2[3]),
                     "+v"(w2[4]), "+v"(w2[5]), "+v"(w2[6]), "+v"(w2[7]),
                     "+v"(w2[8]), "+v"(w2[9]), "+v"(w2[10]), "+v"(w2[11]),
                     "+v"(w2[12]), "+v"(w2[13]), "+v"(w2[14]), "+v"(w2[15]));

            const float inflow = buf[r];
            const v2f in2 = (v2f){inflow, inflow};
            const v2f s2  = (v2f){s, s};
            const v2f zero2 = (v2f)(0.0f);
            v2f acc0 = (v2f)(0.0f);
            v2f acc1 = (v2f)(0.0f);

            #pragma unroll
            for (int g = 0; g < 16; g += 2) {
                v2f z0 = pk_fma(in2, wx[g], pk_fma(s2, wy[g], wb[g]));
                z0 = __builtin_elementwise_max(z0, zero2);
                acc0 = pk_fma(z0, w2[g], acc0);

                v2f z1 = pk_fma(in2, wx[g + 1], pk_fma(s2, wy[g + 1], wb[g + 1]));
                z1 = __builtin_elementwise_max(z1, zero2);
                acc1 = pk_fma(z1, w2[g + 1], acc1);
            }

            float part = (acc0.x + acc1.x) + (acc0.y + acc1.y);
            part = dpp_add<0xB1>(part);    // xor 1
            part = dpp_add<0x4E>(part);    // xor 2
            part = dpp_add<0x141>(part);   // fold the two quads of the 8-lane group
            const float outflow = part + b2v;

            s = fmaf(DT, inflow - outflow, s);   // identical in all 8 lanes

            if (p == 0) {
                *po = outflow;
                *ps = s;
            }
            po += batch;
            ps += batch;
        }

        #pragma unroll
        for (int r = 0; r < 4; ++r) buf[r] = nb[r];
    }

    // Tail for iters % 4 != 0 (dead for iters=512, kept for generality).
    for (int t = tail_start; t < iters; ++t) {
        const float inflow = inp[(size_t)t * batch];
        const v2f in2 = (v2f){inflow, inflow};
        const v2f s2  = (v2f){s, s};
        const v2f zero2 = (v2f)(0.0f);
        v2f acc0 = (v2f)(0.0f), acc1 = (v2f)(0.0f);
        #pragma unroll
        for (int g = 0; g < 16; g += 2) {
            v2f z0 = pk_fma(in2, wx[g], pk_fma(s2, wy[g], wb[g]));
            z0 = __builtin_elementwise_max(z0, zero2);
            acc0 = pk_fma(z0, w2[g], acc0);
            v2f z1 = pk_fma(in2, wx[g + 1], pk_fma(s2, wy[g + 1], wb[g + 1]));
            z1 = __builtin_elementwise_max(z1, zero2);
            acc1 = pk_fma(z1, w2[g + 1], acc1);
        }
        float part = (acc0.x + acc1.x) + (acc0.y + acc1.y);
        part = dpp_add<0xB1>(part);
        part = dpp_add<0x4E>(part);
        part = dpp_add<0x141>(part);
        const float outflow = part + b2v;
        s = fmaf(DT, inflow - outflow, s);
        if (p == 0) {
            *po = outflow;
            *ps = s;
        }
        po += batch;
        ps += batch;
    }
}

extern "C" void kernel_launch(void* const* d_in, const int* in_sizes, int n_in,
                              void* d_out, int out_size, void* d_ws, size_t ws_size,
                              hipStream_t stream) {
    const float* inflows  = (const float*)d_in[0];
    const float* storage0 = (const float*)d_in[1];
    const float* W1       = (const float*)d_in[2];
    const float* b1       = (const float*)d_in[3];
    const float* W2       = (const float*)d_in[4];
    const float* b2       = (const float*)d_in[5];

    int batch  = in_sizes[1];                 // 65536
    int iters  = in_sizes[0] / batch;         // 512
    int hidden = in_sizes[3];                 // 256

    float4* ws = (float4*)d_ws;
    pack_weights<<<(hidden + 255) / 256, 256, 0, stream>>>(W1, b1, W2, ws, hidden);

    float* out_storages = (float*)d_out;                                // (iters+1, batch)
    float* out_outflows = out_storages + (size_t)(iters + 1) * batch;   // (iters, batch)

    int threads = batch * 8;
    waterbalance<<<(threads + 255) / 256, 256, 0, stream>>>(
        inflows, storage0, ws, b2, out_storages, out_outflows, iters, batch);
}

// Round 7
// 1063.995 us; speedup vs baseline: 1.0711x; 1.0711x over previous
//
#include <hip/hip_runtime.h>

#define DT 0.1f

typedef float v2f __attribute__((ext_vector_type(2)));

// Pack per-hidden-unit weights into one float4: (W1[0][j], W1[1][j], b1[j], W2[j])
__global__ void pack_weights(const float* __restrict__ W1, const float* __restrict__ b1,
                             const float* __restrict__ W2, float4* __restrict__ ws, int hidden) {
    int j = blockIdx.x * blockDim.x + threadIdx.x;
    if (j < hidden) {
        ws[j] = make_float4(W1[j], W1[hidden + j], b1[j], W2[j]);
    }
}

// Guaranteed packed fp32 ops (VOP3P; all operands are 64-bit VGPR pairs).
__device__ __forceinline__ v2f pk_fma(v2f a, v2f b, v2f c) {
    v2f d;
    asm("v_pk_fma_f32 %0, %1, %2, %3" : "=v"(d) : "v"(a), "v"(b), "v"(c));
    return d;
}
__device__ __forceinline__ v2f pk_add(v2f a, v2f b) {
    v2f d;
    asm("v_pk_add_f32 %0, %1, %2" : "=v"(d) : "v"(a), "v"(b));
    return d;
}

// DPP-based add-reduce (VALU pipe).
// 0xB1 = quad_perm xor1, 0x4E = quad_perm xor2,
// 0x141 = ROW_HALF_MIRROR (folds quads within each 8-lane half-row),
// 0x140 = ROW_MIRROR (folds the two 8-groups within a 16-lane row).
template <int CTRL>
__device__ __forceinline__ float dpp_add(float x) {
    int v = __builtin_amdgcn_mov_dpp(__float_as_int(x), CTRL, 0xf, 0xf, true);
    return x + __int_as_float(v);
}

// 16 lanes per element: p = lane & 15 owns hidden units [p*16, (p+1)*16).
// Weights = 32 v2f = 64 VGPRs per lane. Rounds 3-6 showed that a 128-reg weight
// set forces AGPR parking + per-use copies (unfixable from source); 64 regs of
// weights + ~30 others fits the 4-waves/SIMD budget (128 regs) architecturally.
__global__ __launch_bounds__(256, 4) void waterbalance(
    const float* __restrict__ inflows, const float* __restrict__ storage0,
    const float4* __restrict__ ws, const float* __restrict__ b2,
    float* __restrict__ out_storages, float* __restrict__ out_outflows,
    int iters, int batch)
{
    const int tid = blockIdx.x * blockDim.x + threadIdx.x;
    const int e = tid >> 4;      // element index
    const int p = tid & 15;      // unit-group within element
    if (e >= batch) return;

    // This lane's 16 units' weights, packed as float2 pairs: 32 v2f = 64 VGPRs.
    v2f wx[8], wy[8], wb[8], w2[8];
    #pragma unroll
    for (int r = 0; r < 8; ++r) {
        float4 a = ws[p * 16 + 2 * r];
        float4 b = ws[p * 16 + 2 * r + 1];
        wx[r] = (v2f){a.x, b.x};
        wy[r] = (v2f){a.y, b.y};
        wb[r] = (v2f){a.z, b.z};
        w2[r] = (v2f){a.w, b.w};
    }
    // Opaque-ify ONCE so the loads cannot be sunk into the time loop.
    #pragma unroll
    for (int r = 0; r < 8; ++r) {
        asm("" : "+v"(wx[r]), "+v"(wy[r]), "+v"(wb[r]), "+v"(w2[r]));
    }

    const float b2v = b2[0];

    float s = storage0[e];
    if (p == 0) out_storages[e] = s;     // storages[0] = storage0

    const float* __restrict__ inp = inflows + e;
    float* __restrict__ po = out_outflows + e;                    // row t
    float* __restrict__ ps = out_storages + (size_t)batch + e;    // row t+1

    const int nchunk = iters >> 2;
    const int tail_start = nchunk << 2;

    // Prefetch chunk 0 (4 steps of inflow in flight).
    float buf[4];
    #pragma unroll
    for (int r = 0; r < 4; ++r) buf[r] = inp[(size_t)r * batch];

    for (int c = 0; c < nchunk; ++c) {
        float nb[4];
        if (c + 1 < nchunk) {
            const float* q = inp + (size_t)(c + 1) * 4 * batch;
            #pragma unroll
            for (int r = 0; r < 4; ++r) nb[r] = q[(size_t)r * batch];
        } else {
            #pragma unroll
            for (int r = 0; r < 4; ++r) nb[r] = 0.0f;
        }

        #pragma unroll
        for (int r = 0; r < 4; ++r) {
            const float inflow = buf[r];
            const v2f in2 = (v2f){inflow, inflow};
            const v2f s2  = (v2f){s, s};
            const v2f zero2 = (v2f)(0.0f);
            v2f acc0 = (v2f)(0.0f);
            v2f acc1 = (v2f)(0.0f);

            #pragma unroll
            for (int g = 0; g < 8; g += 2) {
                v2f z0 = pk_fma(in2, wx[g], pk_fma(s2, wy[g], wb[g]));
                z0 = __builtin_elementwise_max(z0, zero2);
                acc0 = pk_fma(z0, w2[g], acc0);

                v2f z1 = pk_fma(in2, wx[g + 1], pk_fma(s2, wy[g + 1], wb[g + 1]));
                z1 = __builtin_elementwise_max(z1, zero2);
                acc1 = pk_fma(z1, w2[g + 1], acc1);
            }

            v2f accs = pk_add(acc0, acc1);
            float part = accs.x + accs.y;
            part = dpp_add<0xB1>(part);    // xor 1
            part = dpp_add<0x4E>(part);    // xor 2
            part = dpp_add<0x141>(part);   // fold quads within each 8-half
            part = dpp_add<0x140>(part);   // fold the two 8-groups of the 16-row
            const float outflow = part + b2v;

            s = fmaf(DT, inflow - outflow, s);   // identical in all 16 lanes

            if (p == 0) {
                *po = outflow;
                *ps = s;
            }
            po += batch;
            ps += batch;
        }

        #pragma unroll
        for (int r = 0; r < 4; ++r) buf[r] = nb[r];
    }

    // Tail for iters % 4 != 0 (dead for iters=512, kept for generality).
    for (int t = tail_start; t < iters; ++t) {
        const float inflow = inp[(size_t)t * batch];
        const v2f in2 = (v2f){inflow, inflow};
        const v2f s2  = (v2f){s, s};
        const v2f zero2 = (v2f)(0.0f);
        v2f acc0 = (v2f)(0.0f), acc1 = (v2f)(0.0f);
        #pragma unroll
        for (int g = 0; g < 8; g += 2) {
            v2f z0 = pk_fma(in2, wx[g], pk_fma(s2, wy[g], wb[g]));
            z0 = __builtin_elementwise_max(z0, zero2);
            acc0 = pk_fma(z0, w2[g], acc0);
            v2f z1 = pk_fma(in2, wx[g + 1], pk_fma(s2, wy[g + 1], wb[g + 1]));
            z1 = __builtin_elementwise_max(z1, zero2);
            acc1 = pk_fma(z1, w2[g + 1], acc1);
        }
        v2f accs = pk_add(acc0, acc1);
        float part = accs.x + accs.y;
        part = dpp_add<0xB1>(part);
        part = dpp_add<0x4E>(part);
        part = dpp_add<0x141>(part);
        part = dpp_add<0x140>(part);
        const float outflow = part + b2v;
        s = fmaf(DT, inflow - outflow, s);
        if (p == 0) {
            *po = outflow;
            *ps = s;
        }
        po += batch;
        ps += batch;
    }
}

extern "C" void kernel_launch(void* const* d_in, const int* in_sizes, int n_in,
                              void* d_out, int out_size, void* d_ws, size_t ws_size,
                              hipStream_t stream) {
    const float* inflows  = (const float*)d_in[0];
    const float* storage0 = (const float*)d_in[1];
    const float* W1       = (const float*)d_in[2];
    const float* b1       = (const float*)d_in[3];
    const float* W2       = (const float*)d_in[4];
    const float* b2       = (const float*)d_in[5];

    int batch  = in_sizes[1];                 // 65536
    int iters  = in_sizes[0] / batch;         // 512
    int hidden = in_sizes[3];                 // 256

    float4* ws = (float4*)d_ws;
    pack_weights<<<(hidden + 255) / 256, 256, 0, stream>>>(W1, b1, W2, ws, hidden);

    float* out_storages = (float*)d_out;                                // (iters+1, batch)
    float* out_outflows = out_storages + (size_t)(iters + 1) * batch;   // (iters, batch)

    long long threads = (long long)batch * 16;
    waterbalance<<<(int)((threads + 255) / 256), 256, 0, stream>>>(
        inflows, storage0, ws, b2, out_storages, out_outflows, iters, batch);
}